// Round 5
// baseline (561.490 us; speedup 1.0000x reference)
//
#include <hip/hip_runtime.h>
#include <hip/hip_bf16.h>

#define HID 16
#define TLEN 2048
#define WIN 64
#define NW (TLEN / WIN)
#define RSTR 68   // LDS row stride in floats: 272B, 16B-aligned, 2-way bank alias only

typedef float f32x4 __attribute__((ext_vector_type(4)));
typedef short s16x8 __attribute__((ext_vector_type(8)));   // bf16x8 fragment (4 VGPRs)
typedef unsigned int u32x4 __attribute__((ext_vector_type(4)));

#if __has_builtin(__builtin_amdgcn_exp2f)
#define EXP2(x) __builtin_amdgcn_exp2f(x)
#else
#define EXP2(x) __builtin_exp2f(x)
#endif
#if __has_builtin(__builtin_amdgcn_rcpf)
#define RCP(x) __builtin_amdgcn_rcpf(x)
#else
#define RCP(x) (1.0f / (x))
#endif

__device__ __forceinline__ unsigned int pack_bf16(float a, float b) {
    float2 t; t.x = a; t.y = b;
    __hip_bfloat162 p = __float22bfloat162_rn(t);   // v_cvt_pk_bf16_f32, RNE
    unsigned int r;
    __builtin_memcpy(&r, &p, 4);                    // class not trivially copyable;
    return r;                                       // memcpy folds to a bitcast at -O3
}

// sigmoid given u = -log2e * preact  (so sigmoid(a) = 1/(1+2^u))
__device__ __forceinline__ float sigm2(float u) {
    return RCP(1.0f + EXP2(u));
}

// One wave owns 16 sequences. Swapped-operand MFMA per step:
//   C[gate][seq] = (-scale * W_hh_tile) x h^T   via mfma_f32_16x16x32_bf16,
// with only k-slots {0..3} of each 16-lane group populated (upper half zero).
// A and B use the SAME per-lane k-slot mapping, so the contraction pairs
// A-slot i with B-slot i of the same lane group no matter what physical k
// each slot is — correctness needs only: A row = lane&15, B col = lane&15,
// C/D: col=lane&15, row=4*(lane>>4)+reg (m89-verified). By construction each
// lane's 4 C outputs (h_new) are exactly its own next-step B slots 0..3:
// zero cross-lane traffic in the 2048-step recurrence.
__global__ __launch_bounds__(256) void gru_fused(
    const float* __restrict__ x, const float* __restrict__ w_ih,
    const float* __restrict__ w_hh, const float* __restrict__ b_ih,
    const float* __restrict__ b_hh, const float* __restrict__ w_fc,
    const float* __restrict__ b_fc, float* __restrict__ out)
{
    __shared__ float xs[4][2][16 * RSTR];

    const int tid  = threadIdx.x;
    const int wv   = tid >> 6;
    const int lane = tid & 63;
    const int sidx = lane & 15;   // A row / B col / C col = sequence within group
    const int grp  = lane >> 4;   // 0..3: k-slot group and C row group
    const int seq0 = (blockIdx.x * 4 + wv) * 16;

    const float LOG2E = 1.4426950408889634f;
    const float sc[3] = {LOG2E, LOG2E, 2.0f * LOG2E};

    // --- per-lane constants: negated + log2e-scaled weights ---
    s16x8 afr[3];
    f32x4 cini[3];
    float wih0[4], wih1[4], wih2[4], bin[4];
    #pragma unroll
    for (int q = 0; q < 3; ++q) {
        const float s = -sc[q];
        const float* wrow = w_hh + (q * 16 + sidx) * HID + grp * 4;
        u32x4 ua;
        ua.x = pack_bf16(s * wrow[0], s * wrow[1]);
        ua.y = pack_bf16(s * wrow[2], s * wrow[3]);
        ua.z = 0u; ua.w = 0u;                      // unused upper k-slots
        afr[q] = __builtin_bit_cast(s16x8, ua);
        #pragma unroll
        for (int r = 0; r < 4; ++r) {
            int g = q * 16 + grp * 4 + r;
            float bias = b_hh[g] + (q < 2 ? b_ih[g] : 0.0f);
            cini[q][r] = s * bias;
            float w = s * w_ih[g];
            if (q == 0) wih0[r] = w; else if (q == 1) wih1[r] = w; else wih2[r] = w;
        }
    }
    #pragma unroll
    for (int r = 0; r < 4; ++r) bin[r] = -sc[2] * b_ih[32 + grp * 4 + r];

    // --- x staging: lane (sidx, grp) loads 16 floats of row sidx per window ---
    const float* xbase = x + (size_t)(seq0 + sidx) * TLEN + grp * 16;
    const int woff = sidx * RSTR + grp * 16;
    const int roff = sidx * RSTR;

    float* cur = &xs[wv][0][0];
    float* nxt = &xs[wv][1][0];

    f32x4 pf0 = *(const f32x4*)(xbase + 0);
    f32x4 pf1 = *(const f32x4*)(xbase + 4);
    f32x4 pf2 = *(const f32x4*)(xbase + 8);
    f32x4 pf3 = *(const f32x4*)(xbase + 12);
    *(f32x4*)(cur + woff + 0)  = pf0;
    *(f32x4*)(cur + woff + 4)  = pf1;
    *(f32x4*)(cur + woff + 8)  = pf2;
    *(f32x4*)(cur + woff + 12) = pf3;

    float h[4] = {0.f, 0.f, 0.f, 0.f};
    s16x8 bfr;
    { u32x4 z; z.x = 0u; z.y = 0u; z.z = 0u; z.w = 0u;
      bfr = __builtin_bit_cast(s16x8, z); }

    float xcur = cur[roff];   // t = 0 (same-wave LDS write->read is ordered)

    for (int w = 0; w < NW; ++w) {
        const bool more = (w + 1 < NW);
        if (more) {   // prefetch next window into registers (latency hidden)
            const float* xb = xbase + (w + 1) * WIN;
            pf0 = *(const f32x4*)(xb + 0);
            pf1 = *(const f32x4*)(xb + 4);
            pf2 = *(const f32x4*)(xb + 8);
            pf3 = *(const f32x4*)(xb + 12);
        }
        #pragma unroll 4
        for (int tt = 0; tt < WIN; ++tt) {
            float xnext = cur[roff + ((tt + 1) & (WIN - 1))];

            f32x4 c0 = __builtin_amdgcn_mfma_f32_16x16x32_bf16(afr[0], bfr, cini[0], 0, 0, 0);
            f32x4 c1 = __builtin_amdgcn_mfma_f32_16x16x32_bf16(afr[1], bfr, cini[1], 0, 0, 0);
            f32x4 c2 = __builtin_amdgcn_mfma_f32_16x16x32_bf16(afr[2], bfr, cini[2], 0, 0, 0);

            #pragma unroll
            for (int i = 0; i < 4; ++i) {
                // all preactivations are NEGATED and log2e-scaled
                float rr = sigm2(fmaf(xcur, wih0[i], c0[i]));
                float zz = sigm2(fmaf(xcur, wih1[i], c1[i]));
                float un = fmaf(xcur, wih2[i], bin[i]);
                un = fmaf(rr, c2[i], un);
                float nn = fmaf(2.0f, sigm2(un), -1.0f);   // tanh
                h[i] = fmaf(zz, h[i] - nn, nn);            // (1-z)*n + z*h
            }
            u32x4 uu;
            uu.x = pack_bf16(h[0], h[1]);
            uu.y = pack_bf16(h[2], h[3]);
            uu.z = 0u; uu.w = 0u;
            bfr = __builtin_bit_cast(s16x8, uu);
            xcur = xnext;
        }
        if (more) {
            *(f32x4*)(nxt + woff + 0)  = pf0;
            *(f32x4*)(nxt + woff + 4)  = pf1;
            *(f32x4*)(nxt + woff + 8)  = pf2;
            *(f32x4*)(nxt + woff + 12) = pf3;
            float* t = cur; cur = nxt; nxt = t;
            xcur = cur[roff];   // first x of the new window, via same LDS path
        }
    }

    // --- fc epilogue on final h ---
    float p = h[0] * w_fc[grp * 4 + 0] + h[1] * w_fc[grp * 4 + 1] +
              h[2] * w_fc[grp * 4 + 2] + h[3] * w_fc[grp * 4 + 3];
    p += __shfl_xor(p, 16, 64);
    p += __shfl_xor(p, 32, 64);
    if (grp == 0) out[seq0 + sidx] = p + b_fc[0];
}

extern "C" void kernel_launch(void* const* d_in, const int* in_sizes, int n_in,
                              void* d_out, int out_size, void* d_ws, size_t ws_size,
                              hipStream_t stream) {
    const float* x    = (const float*)d_in[0];
    const float* w_ih = (const float*)d_in[1];
    const float* w_hh = (const float*)d_in[2];
    const float* b_ih = (const float*)d_in[3];
    const float* b_hh = (const float*)d_in[4];
    const float* w_fc = (const float*)d_in[5];
    const float* b_fc = (const float*)d_in[6];
    float* out = (float*)d_out;

    const int B = in_sizes[0] / TLEN;   // x is [B, T, 1]
    dim3 grid(B / 64), block(256);
    gru_fused<<<grid, block, 0, stream>>>(x, w_ih, w_hh, b_ih, b_hh, w_fc, b_fc, out);
}